// Round 5
// baseline (37.333 us; speedup 1.0000x reference)
//
#include <hip/hip_runtime.h>
#include <math.h>

#define ROW 345              // 115 joints * 3 dwords per frame
#define NFRAMES 100000
#define OUTROWS 200
#define FEAT 1198
#define Q4 8625000u          // total float4 in input: 100000*345/4
#define CBLOCKS 4212         // ceil(Q4 / (256*8))
#define CDEPTH 8             // float4 loads in flight per thread
#define NT (CBLOCKS * 256u)  // threads in count grid

// Dense float4 stream over the whole input. Each dword d is classified by
// r = d mod 345: left hand [120,183) -> +nonzero, right hand [282,345) ->
// -nonzero. Per-block partial sum stored to part[bid] (no atomics, no init).
__global__ void count_kernel(const float4* __restrict__ x4, int* __restrict__ part) {
    const unsigned gtid = blockIdx.x * 256u + threadIdx.x;

    float4 v[CDEPTH];
    #pragma unroll
    for (int u = 0; u < CDEPTH; ++u) {
        unsigned q = gtid + (unsigned)u * NT;
        unsigned qc = (q < Q4) ? q : (Q4 - 1u);   // clamp; masked below
        v[u] = x4[qc];
    }

    int cnt = 0;
    #pragma unroll
    for (int u = 0; u < CDEPTH; ++u) {
        unsigned q = gtid + (unsigned)u * NT;
        if (q < Q4) {
            unsigned d0 = 4u * q;
            unsigned f  = d0 / 345u;              // magic-mul
            unsigned r0 = d0 - f * 345u;
            const float w[4] = { v[u].x, v[u].y, v[u].z, v[u].w };
            #pragma unroll
            for (int k = 0; k < 4; ++k) {
                unsigned r = r0 + (unsigned)k;
                r = (r >= 345u) ? (r - 345u) : r;
                float a = w[k];
                int nz = (a == a && a != 0.0f) ? 1 : 0;   // NaN -> 0
                if (r - 120u < 63u) cnt += nz;            // left
                else if (r - 282u < 63u) cnt -= nz;       // right
            }
        }
    }

    // block reduction -> one plain store
    #pragma unroll
    for (int s = 32; s > 0; s >>= 1) cnt += __shfl_down(cnt, s, 64);
    __shared__ int red[4];
    const int lane = threadIdx.x & 63, wv = threadIdx.x >> 6;
    if (lane == 0) red[wv] = cnt;
    __syncthreads();
    if (threadIdx.x == 0) part[blockIdx.x] = red[0] + red[1] + red[2] + red[3];
}

__global__ void feat_kernel(const float* __restrict__ x,
                            const int* __restrict__ part,
                            float* __restrict__ out) {
    __shared__ float xf0[86][3];
    __shared__ float xf1[86][3];
    __shared__ float s_handsum;
    __shared__ int s_tot;

    // Reduce the 4212 count partials (L2-hot, shared by all 200 blocks)
    int psum = 0;
    for (int i = threadIdx.x; i < CBLOCKS; i += 256) psum += part[i];
    #pragma unroll
    for (int s = 32; s > 0; s >>= 1) psum += __shfl_down(psum, s, 64);
    __shared__ int red[4];
    const int lane = threadIdx.x & 63, wv = threadIdx.x >> 6;
    if (lane == 0) red[wv] = psum;
    __syncthreads();
    if (threadIdx.x == 0) s_tot = red[0] + red[1] + red[2] + red[3];
    __syncthreads();

    const int t = blockIdx.x;
    const bool cond = s_tot > 0;
    const int handbase = cond ? 120 : 282;

    // Build xfeat rows t and t+1 (86 joints x 3), NaN-cleaned, x mirrored if cond
    for (int q = threadIdx.x; q < 2 * 258; q += blockDim.x) {
        int which = q / 258;
        int e = q - which * 258;
        int k = e / 3, c = e - k * 3;
        int src;
        if (k < 21)      src = handbase + k * 3 + c;          // hand
        else if (k < 46) src = 183 + (k - 21) * 3 + c;        // pose (61:86)
        else             src = (k - 46) * 3 + c;              // lip (0:40)
        int row = t + which;
        float v = x[(long long)row * ROW + src];
        if (v != v) v = 0.0f;
        if (c == 0 && cond) v = -v;
        if (which == 0) xf0[k][c] = v; else xf1[k][c] = v;
    }
    __syncthreads();

    if (threadIdx.x == 0) {
        float s = 0.0f;
        for (int k = 0; k < 21; ++k)
            for (int c = 0; c < 3; ++c) {
                float v = xf0[k][c];
                if (c == 0 && cond) v = -v;   // undo mirror: raw hand values
                s += v;
            }
        s_handsum = s;
    }
    __syncthreads();

    const float hand_mask = (s_handsum != 0.0f) ? 1.0f : 0.0f;
    float* o = out + (long long)t * FEAT;

    for (int q = threadIdx.x; q < FEAT; q += blockDim.x) {
        float v;
        if (q < 63) {
            int k = q / 3, c = q % 3; v = xf0[k][c];
        } else if (q < 113) {
            int p = q - 63; int k = 21 + p / 2, c = p & 1; v = xf0[k][c];
        } else if (q < 153) {
            int p = q - 113; int k = 46 + p / 2, c = p & 1; v = xf0[k][c];
        } else if (q < 216) {
            int p = q - 153; int k = p / 3, c = p % 3; v = xf0[k][c] - xf1[k][c];
        } else if (q < 266) {
            int p = q - 216; int k = 21 + p / 2, c = p & 1; v = xf0[k][c] - xf1[k][c];
        } else if (q < 306) {
            int p = q - 266; int k = 46 + p / 2, c = p & 1; v = xf0[k][c] - xf1[k][c];
        } else if (q < 516) {              // hdist: 21 joints, 3D
            int p = q - 306, n = 21, i = 0, rem = p;
            while (rem >= n - 1 - i) { rem -= n - 1 - i; ++i; }
            int j = i + 1 + rem;
            float dx = xf0[i][0] - xf0[j][0];
            float dy = xf0[i][1] - xf0[j][1];
            float dz = xf0[i][2] - xf0[j][2];
            v = sqrtf(dx * dx + dy * dy + dz * dz);
        } else if (q < 816) {              // pdist: joints 21:46, 2D
            int p = q - 516, n = 25, i = 0, rem = p;
            while (rem >= n - 1 - i) { rem -= n - 1 - i; ++i; }
            int j = i + 1 + rem; int a = 21 + i, b = 21 + j;
            float dx = xf0[a][0] - xf0[b][0];
            float dy = xf0[a][1] - xf0[b][1];
            v = sqrtf(dx * dx + dy * dy);
        } else if (q < 1006) {             // oldist: joints 46:66, 2D
            int p = q - 816, n = 20, i = 0, rem = p;
            while (rem >= n - 1 - i) { rem -= n - 1 - i; ++i; }
            int j = i + 1 + rem; int a = 46 + i, b = 46 + j;
            float dx = xf0[a][0] - xf0[b][0];
            float dy = xf0[a][1] - xf0[b][1];
            v = sqrtf(dx * dx + dy * dy);
        } else if (q < 1196) {             // ildist: joints 66:86, 2D
            int p = q - 1006, n = 20, i = 0, rem = p;
            while (rem >= n - 1 - i) { rem -= n - 1 - i; ++i; }
            int j = i + 1 + rem; int a = 66 + i, b = 66 + j;
            float dx = xf0[a][0] - xf0[b][0];
            float dy = xf0[a][1] - xf0[b][1];
            v = sqrtf(dx * dx + dy * dy);
        } else if (q == 1196) {
            v = hand_mask;
        } else {
            v = hand_mask + 1.0f;
        }
        o[q] = v;
    }
}

extern "C" void kernel_launch(void* const* d_in, const int* in_sizes, int n_in,
                              void* d_out, int out_size, void* d_ws, size_t ws_size,
                              hipStream_t stream) {
    const float* x = (const float*)d_in[0];
    float* out = (float*)d_out;
    int* part = (int*)d_ws;

    count_kernel<<<CBLOCKS, 256, 0, stream>>>((const float4*)x, part);
    feat_kernel<<<OUTROWS, 256, 0, stream>>>(x, part, out);
}

// Round 6
// 25.077 us; speedup vs baseline: 1.4887x; 1.4887x over previous
//
#include <hip/hip_runtime.h>
#include <math.h>

#define ROW 345              // dwords per frame
#define NFRAMES 100000
#define OUTROWS 200
#define FEAT 1198
#define SFD 5                // superframes per wave
#define CBLK 1250            // blocks: 1250*4 waves*5 sf = 25000 superframes

// Count (#nonzero lefth - #nonzero righth) via superframe-aligned float4 slots.
// 4 frames = 345 float4 exactly; the 8 hand ranges per superframe are covered
// by 132 compile-time float4 slots. Lane l owns slots l, 64+l, 128+l (weights
// zero outside hand dwords / for slots >= 132).
__global__ void count_kernel(const float4* __restrict__ x4, int* __restrict__ part) {
    const int lane = threadIdx.x & 63;
    const int wv   = threadIdx.x >> 6;

    // Decode this lane's 3 slots: float4 index q within superframe + 4 weights
    int q[3];
    int w[3][4];
    #pragma unroll
    for (int t3 = 0; t3 < 3; ++t3) {
        int k = 64 * t3 + lane;
        int qq = 0, sgn = 0, st = -1;
        int pre = 0;
        #pragma unroll
        for (int r = 0; r < 8; ++r) {          // L0,R0,L1,R1,... ascending
            int j = r >> 1, side = r & 1;
            int s_r = 345 * j + (side ? 282 : 120);
            int qlo = s_r >> 2, qhi = (s_r + 62) >> 2;
            int c_r = qhi - qlo + 1;
            if (k >= pre && k < pre + c_r) {
                qq = qlo + (k - pre);
                sgn = side ? -1 : 1;
                st = s_r;
            }
            pre += c_r;                         // pre ends at 132
        }
        q[t3] = qq;
        #pragma unroll
        for (int c = 0; c < 4; ++c) {
            int dw = 4 * qq + c;
            w[t3][c] = (st >= 0 && dw >= st && dw < st + 63) ? sgn : 0;
        }
    }

    const int gw  = blockIdx.x * 4 + wv;        // global wave id, 0..4999
    const int sf0 = gw * SFD;

    // Issue all 15 independent loads before any use
    float4 v[SFD][3];
    #pragma unroll
    for (int d = 0; d < SFD; ++d) {
        size_t b = (size_t)(sf0 + d) * 345;
        v[d][0] = x4[b + q[0]];
        v[d][1] = x4[b + q[1]];
        v[d][2] = x4[b + q[2]];                 // lanes>=4: q=0, w=0 (1 line/wave)
    }

    int cnt = 0;
    #pragma unroll
    for (int d = 0; d < SFD; ++d) {
        #pragma unroll
        for (int t3 = 0; t3 < 3; ++t3) {
            const float a0 = v[d][t3].x, a1 = v[d][t3].y, a2 = v[d][t3].z, a3 = v[d][t3].w;
            cnt += ((a0 == a0) && (a0 != 0.0f)) ? w[t3][0] : 0;   // NaN -> 0
            cnt += ((a1 == a1) && (a1 != 0.0f)) ? w[t3][1] : 0;
            cnt += ((a2 == a2) && (a2 != 0.0f)) ? w[t3][2] : 0;
            cnt += ((a3 == a3) && (a3 != 0.0f)) ? w[t3][3] : 0;
        }
    }

    #pragma unroll
    for (int s = 32; s > 0; s >>= 1) cnt += __shfl_down(cnt, s, 64);
    __shared__ int red[4];
    if (lane == 0) red[wv] = cnt;
    __syncthreads();
    if (threadIdx.x == 0) part[blockIdx.x] = red[0] + red[1] + red[2] + red[3];
}

__global__ void feat_kernel(const float* __restrict__ x,
                            const int* __restrict__ part,
                            float* __restrict__ out) {
    __shared__ float xf0[86][3];
    __shared__ float xf1[86][3];
    __shared__ float s_handsum;
    __shared__ int s_tot;
    __shared__ int red[4];

    // Reduce the 1250 count partials (L2-hot, shared across the 200 blocks)
    int psum = 0;
    for (int i = threadIdx.x; i < CBLK; i += 256) psum += part[i];
    #pragma unroll
    for (int s = 32; s > 0; s >>= 1) psum += __shfl_down(psum, s, 64);
    const int lane = threadIdx.x & 63, wv = threadIdx.x >> 6;
    if (lane == 0) red[wv] = psum;
    __syncthreads();
    if (threadIdx.x == 0) s_tot = red[0] + red[1] + red[2] + red[3];
    __syncthreads();

    const int t = blockIdx.x;
    const bool cond = s_tot > 0;
    const int handbase = cond ? 120 : 282;

    for (int qi = threadIdx.x; qi < 2 * 258; qi += blockDim.x) {
        int which = qi / 258;
        int e = qi - which * 258;
        int k = e / 3, c = e - k * 3;
        int src;
        if (k < 21)      src = handbase + k * 3 + c;          // hand
        else if (k < 46) src = 183 + (k - 21) * 3 + c;        // pose (61:86)
        else             src = (k - 46) * 3 + c;              // lip (0:40)
        int row = t + which;
        float v = x[(long long)row * ROW + src];
        if (v != v) v = 0.0f;
        if (c == 0 && cond) v = -v;
        if (which == 0) xf0[k][c] = v; else xf1[k][c] = v;
    }
    __syncthreads();

    if (threadIdx.x == 0) {
        float s = 0.0f;
        for (int k = 0; k < 21; ++k)
            for (int c = 0; c < 3; ++c) {
                float v = xf0[k][c];
                if (c == 0 && cond) v = -v;   // raw hand values for the mask
                s += v;
            }
        s_handsum = s;
    }
    __syncthreads();

    const float hand_mask = (s_handsum != 0.0f) ? 1.0f : 0.0f;
    float* o = out + (long long)t * FEAT;

    for (int q = threadIdx.x; q < FEAT; q += blockDim.x) {
        float v;
        if (q < 63) {
            int k = q / 3, c = q % 3; v = xf0[k][c];
        } else if (q < 113) {
            int p = q - 63; int k = 21 + p / 2, c = p & 1; v = xf0[k][c];
        } else if (q < 153) {
            int p = q - 113; int k = 46 + p / 2, c = p & 1; v = xf0[k][c];
        } else if (q < 216) {
            int p = q - 153; int k = p / 3, c = p % 3; v = xf0[k][c] - xf1[k][c];
        } else if (q < 266) {
            int p = q - 216; int k = 21 + p / 2, c = p & 1; v = xf0[k][c] - xf1[k][c];
        } else if (q < 306) {
            int p = q - 266; int k = 46 + p / 2, c = p & 1; v = xf0[k][c] - xf1[k][c];
        } else if (q < 516) {              // hdist: 21 joints, 3D
            int p = q - 306, n = 21, i = 0, rem = p;
            while (rem >= n - 1 - i) { rem -= n - 1 - i; ++i; }
            int j = i + 1 + rem;
            float dx = xf0[i][0] - xf0[j][0];
            float dy = xf0[i][1] - xf0[j][1];
            float dz = xf0[i][2] - xf0[j][2];
            v = sqrtf(dx * dx + dy * dy + dz * dz);
        } else if (q < 816) {              // pdist: joints 21:46, 2D
            int p = q - 516, n = 25, i = 0, rem = p;
            while (rem >= n - 1 - i) { rem -= n - 1 - i; ++i; }
            int j = i + 1 + rem; int a = 21 + i, b = 21 + j;
            float dx = xf0[a][0] - xf0[b][0];
            float dy = xf0[a][1] - xf0[b][1];
            v = sqrtf(dx * dx + dy * dy);
        } else if (q < 1006) {             // oldist: joints 46:66, 2D
            int p = q - 816, n = 20, i = 0, rem = p;
            while (rem >= n - 1 - i) { rem -= n - 1 - i; ++i; }
            int j = i + 1 + rem; int a = 46 + i, b = 46 + j;
            float dx = xf0[a][0] - xf0[b][0];
            float dy = xf0[a][1] - xf0[b][1];
            v = sqrtf(dx * dx + dy * dy);
        } else if (q < 1196) {             // ildist: joints 66:86, 2D
            int p = q - 1006, n = 20, i = 0, rem = p;
            while (rem >= n - 1 - i) { rem -= n - 1 - i; ++i; }
            int j = i + 1 + rem; int a = 66 + i, b = 66 + j;
            float dx = xf0[a][0] - xf0[b][0];
            float dy = xf0[a][1] - xf0[b][1];
            v = sqrtf(dx * dx + dy * dy);
        } else if (q == 1196) {
            v = hand_mask;
        } else {
            v = hand_mask + 1.0f;
        }
        o[q] = v;
    }
}

extern "C" void kernel_launch(void* const* d_in, const int* in_sizes, int n_in,
                              void* d_out, int out_size, void* d_ws, size_t ws_size,
                              hipStream_t stream) {
    const float* x = (const float*)d_in[0];
    float* out = (float*)d_out;
    int* part = (int*)d_ws;

    count_kernel<<<CBLK, 256, 0, stream>>>((const float4*)x, part);
    feat_kernel<<<OUTROWS, 256, 0, stream>>>(x, part, out);
}